// Round 1
// baseline (98.116 us; speedup 1.0000x reference)
//
#include <hip/hip_runtime.h>
#include <stdint.h>

#define BDIM 256
#define T_   66
#define EMB  128
#define NS   24
#define NM   40
#define NI   70
#define CONT 32
#define OUTW 21408   // 32 + 66*128 + 66*128 + 70*64

typedef __attribute__((ext_vector_type(4))) float f32x4;
typedef __attribute__((ext_vector_type(8))) unsigned short u16x8;
typedef __attribute__((ext_vector_type(8))) __bf16 bf16x8;

static __device__ __forceinline__ unsigned short f2bf(float x) {
  union { float f; unsigned u; } v; v.f = x;
  unsigned r = (v.u + 0x7FFFu + ((v.u >> 16) & 1u)) >> 16;
  return (unsigned short)r;
}

static __device__ __forceinline__ f32x4 mfma16(u16x8 a, u16x8 b, f32x4 c) {
  return __builtin_amdgcn_mfma_f32_16x16x32_bf16(
      __builtin_bit_cast(bf16x8, a), __builtin_bit_cast(bf16x8, b), c, 0, 0, 0);
}

// ---------------------------------------------------------------------------
// Kernel 0: batch-independent precompute.
//  blocks 0..65   : screen MLP, t = blockIdx  -> base_h_s[t][128] (pre-relu),
//                   base_out_s[t][128] (full MLP with zero feats)
//  blocks 66..131 : minimap MLP, t = blockIdx-66
//  block 132/133  : Ws2 / Wm2 -> bf16, pre-swizzled into MFMA B-frag order:
//                   dst[((n*4+kk)*64 + lane)*8 + e] = W2[kk*32+(lane>>4)*8+e][n*16+(lane&15)]
// ---------------------------------------------------------------------------
__global__ __launch_bounds__(BDIM) void precomp(
    const float* __restrict__ char_emb,
    const float* __restrict__ Ws1, const float* __restrict__ bs1,
    const float* __restrict__ Ws2, const float* __restrict__ bs2,
    const float* __restrict__ Wm1, const float* __restrict__ bm1,
    const float* __restrict__ Wm2, const float* __restrict__ bm2,
    float* __restrict__ base_h_s, float* __restrict__ base_h_m,
    float* __restrict__ base_out_s, float* __restrict__ base_out_m,
    unsigned short* __restrict__ w2s_swz, unsigned short* __restrict__ w2m_swz) {
  const int bb = blockIdx.x, tid = threadIdx.x;
  if (bb < 132) {
    const int mlp = bb / T_, t = bb % T_;
    const float* W1 = mlp ? Wm1 : Ws1;
    const float* W2 = mlp ? Wm2 : Ws2;
    const float* b1 = mlp ? bm1 : bs1;
    const float* b2 = mlp ? bm2 : bs2;
    float* bh = mlp ? base_h_m : base_h_s;
    float* bo = mlp ? base_out_m : base_out_s;
    __shared__ float h[EMB];
    if (tid < EMB) {
      float acc = b1[tid];
      for (int f = 0; f < EMB; ++f) acc += char_emb[t * EMB + f] * W1[f * EMB + tid];
      bh[t * EMB + tid] = acc;           // pre-relu (needed for feat correction)
      h[tid] = fmaxf(acc, 0.f);
    }
    __syncthreads();
    if (tid < EMB) {
      float acc = b2[tid];
      for (int i = 0; i < EMB; ++i) acc += h[i] * W2[i * EMB + tid];
      bo[t * EMB + tid] = acc;
    }
  } else {
    const int mlp = bb - 132;
    const float* W2 = mlp ? Wm2 : Ws2;
    unsigned short* dst = mlp ? w2m_swz : w2s_swz;
    for (int idx = tid; idx < 8 * 4 * 64 * 8; idx += BDIM) {
      const int e = idx & 7, lane = (idx >> 3) & 63, kk = (idx >> 9) & 3, n = idx >> 11;
      const int k = kk * 32 + (lane >> 4) * 8 + e;
      const int col = n * 16 + (lane & 15);
      dst[idx] = f2bf(W2[k * EMB + col]);
    }
  }
}

// ---------------------------------------------------------------------------
// Kernel 1: one block per sample.
// ---------------------------------------------------------------------------
__global__ __launch_bounds__(BDIM) void fused(
    const float* __restrict__ contf,
    const float* __restrict__ sfeat,
    const float* __restrict__ mfeat,
    const float* __restrict__ item_emb,
    const float* __restrict__ Ws1,
    const float* __restrict__ bs2,
    const float* __restrict__ Wm1,
    const float* __restrict__ bm2,
    const int* __restrict__ sids,
    const int* __restrict__ mids,
    const int* __restrict__ items,
    const float* __restrict__ base_h_s, const float* __restrict__ base_h_m,
    const float* __restrict__ base_out_s, const float* __restrict__ base_out_m,
    const unsigned short* __restrict__ w2s_swz, const unsigned short* __restrict__ w2m_swz,
    float* __restrict__ out) {
  const int b = blockIdx.x, tid = threadIdx.x;

  __shared__ int s_map[T_], m_map[T_];
  __shared__ int s_id[NS], m_id[NM], s_item[NI];
  __shared__ float s_f[NS * 4], m_f[NM * 2];
  __shared__ u16x8 h_frag[5 * 4 * 64];      // bf16 A-fragments, 20 KB
  __shared__ float det_out[48 * 132];       // fp32 det rows, stride 132 (bank pad)

  // ---- phase 1: init maps, stage ids/feats/items ----
  if (tid < T_) { s_map[tid] = -1; m_map[tid] = -1; }
  if (tid < NS) s_id[tid] = sids[b * NS + tid];
  if (tid < NM) m_id[tid] = mids[b * NM + tid];
  if (tid < NI) s_item[tid] = items[b * NI + tid];
  if (tid < NS * 4) s_f[tid] = sfeat[b * NS * 4 + tid];
  if (tid < NM * 2) m_f[tid] = mfeat[b * NM * 2 + tid];
  __syncthreads();
  if (tid < NS) s_map[s_id[tid]] = tid;     // unique ids per sample
  if (tid < NM) m_map[m_id[tid]] = tid;

  // ---- phase 2: detection h -> bf16 A-fragment layout ----
  // unit u = (tile*4+kk)*64 + lane; tiles 0-1 screen (M=24+pad), 2-4 mini (M=40+pad)
  for (int u = tid; u < 5 * 4 * 64; u += BDIM) {
    const int lane = u & 63, kk = (u >> 6) & 3, tile = u >> 8;
    const int g = lane >> 4, r = lane & 15;
    const int k0 = kk * 32 + g * 8;
    const bool scr = tile < 2;
    const int j = scr ? tile * 16 + r : (tile - 2) * 16 + r;
    const int nd = scr ? NS : NM;
    float v[8];
    if (j < nd) {
      const int t = scr ? s_id[j] : m_id[j];
      const float* bh = (scr ? base_h_s : base_h_m) + t * EMB + k0;
#pragma unroll
      for (int e = 0; e < 8; ++e) v[e] = bh[e];
      if (scr) {
        const float* fp = &s_f[j * 4];
#pragma unroll
        for (int c = 0; c < 4; ++c) {
          const float fc = fp[c];
          const float* w = Ws1 + (128 + c) * EMB + k0;
#pragma unroll
          for (int e = 0; e < 8; ++e) v[e] += fc * w[e];
        }
      } else {
        const float* fp = &m_f[j * 2];
#pragma unroll
        for (int c = 0; c < 2; ++c) {
          const float fc = fp[c];
          const float* w = Wm1 + (128 + c) * EMB + k0;
#pragma unroll
          for (int e = 0; e < 8; ++e) v[e] += fc * w[e];
        }
      }
#pragma unroll
      for (int e = 0; e < 8; ++e) v[e] = fmaxf(v[e], 0.f);
    } else {
#pragma unroll
      for (int e = 0; e < 8; ++e) v[e] = 0.f;  // padding rows: keep MFMA NaN-free
    }
    u16x8 pk;
#pragma unroll
    for (int e = 0; e < 8; ++e) pk[e] = f2bf(v[e]);
    h_frag[u] = pk;
  }
  __syncthreads();

  // ---- phase 2.5: continuous + item gather (pure copies, fp32 exact) ----
  {
    f32x4* ob = reinterpret_cast<f32x4*>(out + (size_t)b * OUTW);
    const f32x4* cb = reinterpret_cast<const f32x4*>(contf + (size_t)b * CONT);
    for (int u = tid; u < 8 + NI * 16; u += BDIM) {
      if (u < 8) {
        __builtin_nontemporal_store(cb[u], &ob[u]);
      } else {
        const int v2 = u - 8, j = v2 >> 4, q = v2 & 15;
        const int it = s_item[j];
        const f32x4 src = reinterpret_cast<const f32x4*>(item_emb + it * 64)[q];
        __builtin_nontemporal_store(src, reinterpret_cast<f32x4*>(
            out + (size_t)b * OUTW + (CONT + 2 * T_ * EMB) + j * 64) + q);
      }
    }
  }

  const int w = tid >> 6, lane = tid & 63;
  const int g = lane >> 4, r = lane & 15;
  const int n0 = w * 2;   // this wave owns output cols [n0*16, (n0+2)*16)

  // ---- phase 3: screen detection GEMM (M tiles 0-1) ----
  {
    u16x8 bS[2][4];
    float biasS[2];
#pragma unroll
    for (int n = 0; n < 2; ++n) {
      biasS[n] = bs2[(n0 + n) * 16 + r];
#pragma unroll
      for (int kk = 0; kk < 4; ++kk)
        bS[n][kk] = reinterpret_cast<const u16x8*>(w2s_swz)[((n0 + n) * 4 + kk) * 64 + lane];
    }
#pragma unroll
    for (int m = 0; m < 2; ++m) {
#pragma unroll
      for (int n = 0; n < 2; ++n) {
        f32x4 acc = {0.f, 0.f, 0.f, 0.f};
#pragma unroll
        for (int kk = 0; kk < 4; ++kk)
          acc = mfma16(h_frag[(m * 4 + kk) * 64 + lane], bS[n][kk], acc);
        const int col = (n0 + n) * 16 + r;
#pragma unroll
        for (int q = 0; q < 4; ++q)
          det_out[(m * 16 + g * 4 + q) * 132 + col] = acc[q] + biasS[n];
      }
    }
  }
  __syncthreads();

  // ---- phase 4: screen epilogue (every row written exactly once) ----
  {
    float* outp = out + (size_t)b * OUTW + CONT;
    for (int u = tid; u < T_ * 32; u += BDIM) {
      const int t = u >> 5, q = u & 31;
      const int d = s_map[t];
      f32x4 v;
      if (d >= 0) v = *reinterpret_cast<const f32x4*>(&det_out[d * 132 + q * 4]);
      else        v = reinterpret_cast<const f32x4*>(base_out_s + t * EMB)[q];
      __builtin_nontemporal_store(v, reinterpret_cast<f32x4*>(outp + t * EMB) + q);
    }
  }
  __syncthreads();

  // ---- phase 5: minimap detection GEMM (M tiles 2-4) ----
  {
    u16x8 bM[2][4];
    float biasM[2];
#pragma unroll
    for (int n = 0; n < 2; ++n) {
      biasM[n] = bm2[(n0 + n) * 16 + r];
#pragma unroll
      for (int kk = 0; kk < 4; ++kk)
        bM[n][kk] = reinterpret_cast<const u16x8*>(w2m_swz)[((n0 + n) * 4 + kk) * 64 + lane];
    }
#pragma unroll
    for (int m = 0; m < 3; ++m) {
#pragma unroll
      for (int n = 0; n < 2; ++n) {
        f32x4 acc = {0.f, 0.f, 0.f, 0.f};
#pragma unroll
        for (int kk = 0; kk < 4; ++kk)
          acc = mfma16(h_frag[((m + 2) * 4 + kk) * 64 + lane], bM[n][kk], acc);
        const int col = (n0 + n) * 16 + r;
#pragma unroll
        for (int q = 0; q < 4; ++q)
          det_out[(m * 16 + g * 4 + q) * 132 + col] = acc[q] + biasM[n];
      }
    }
  }
  __syncthreads();

  // ---- phase 6: minimap epilogue ----
  {
    float* outp = out + (size_t)b * OUTW + CONT + T_ * EMB;
    for (int u = tid; u < T_ * 32; u += BDIM) {
      const int t = u >> 5, q = u & 31;
      const int d = m_map[t];
      f32x4 v;
      if (d >= 0) v = *reinterpret_cast<const f32x4*>(&det_out[d * 132 + q * 4]);
      else        v = reinterpret_cast<const f32x4*>(base_out_m + t * EMB)[q];
      __builtin_nontemporal_store(v, reinterpret_cast<f32x4*>(outp + t * EMB) + q);
    }
  }
}

// ---------------------------------------------------------------------------
extern "C" void kernel_launch(void* const* d_in, const int* in_sizes, int n_in,
                              void* d_out, int out_size, void* d_ws, size_t ws_size,
                              hipStream_t stream) {
  const float* contf    = (const float*)d_in[0];
  const float* sfeat    = (const float*)d_in[1];
  const float* mfeat    = (const float*)d_in[2];
  const float* char_emb = (const float*)d_in[3];
  const float* item_emb = (const float*)d_in[4];
  const float* Ws1 = (const float*)d_in[5];
  const float* bs1 = (const float*)d_in[6];
  const float* Ws2 = (const float*)d_in[7];
  const float* bs2 = (const float*)d_in[8];
  const float* Wm1 = (const float*)d_in[9];
  const float* bm1 = (const float*)d_in[10];
  const float* Wm2 = (const float*)d_in[11];
  const float* bm2 = (const float*)d_in[12];
  const int* sids  = (const int*)d_in[13];
  const int* mids  = (const int*)d_in[14];
  const int* items = (const int*)d_in[15];
  float* out = (float*)d_out;

  const int B = in_sizes[0] / CONT;

  // workspace layout (bytes): 4x base tables (33792 each) + 2x bf16 W2 (32768 each)
  char* ws = (char*)d_ws;
  float* base_h_s   = (float*)(ws + 0);
  float* base_h_m   = (float*)(ws + 33792);
  float* base_out_s = (float*)(ws + 67584);
  float* base_out_m = (float*)(ws + 101376);
  unsigned short* w2s = (unsigned short*)(ws + 135168);
  unsigned short* w2m = (unsigned short*)(ws + 167936);

  precomp<<<134, BDIM, 0, stream>>>(char_emb, Ws1, bs1, Ws2, bs2, Wm1, bm1, Wm2, bm2,
                                    base_h_s, base_h_m, base_out_s, base_out_m, w2s, w2m);
  fused<<<B, BDIM, 0, stream>>>(contf, sfeat, mfeat, item_emb, Ws1, bs2, Wm1, bm2,
                                sids, mids, items,
                                base_h_s, base_h_m, base_out_s, base_out_m, w2s, w2m, out);
}